// Round 2
// baseline (1710.874 us; speedup 1.0000x reference)
//
#include <hip/hip_runtime.h>
#include <hip/hip_bf16.h>
#include <math.h>

// LGCN layer, CSR-bucketed (no f32 atomics):
//   agg = segsum(atten*src) @ W_rel          (W_rel commutes out of the sum)
//   att_logit = s1[src] + s2[dst]            (lin_w splits into two per-node dots)
// Pipeline: memset offs -> precompute s1/s2 -> dst histogram -> 1-block scan ->
//           scatter (src,att) into dst buckets -> wave-per-node gather-reduce
//           fused with W_rel/loop matvecs + tanh epilogue.

#define D 64

// ---------------- kernel 1: per-node attention scalars ----------------
__global__ __launch_bounds__(256) void precompute_att(
    const float* __restrict__ feat, const float* __restrict__ lin_w,
    const float* __restrict__ lin_b, float* __restrict__ s1,
    float* __restrict__ s2, int N) {
  const int lane = threadIdx.x & 63;
  const int wid  = (blockIdx.x * blockDim.x + threadIdx.x) >> 6;
  const int nw   = (gridDim.x * blockDim.x) >> 6;
  const float w1 = lin_w[lane];
  const float w2 = lin_w[64 + lane];
  const float b  = lin_b[0];
  for (int i = wid; i < N; i += nw) {
    const float f = feat[(size_t)i * D + lane];
    float v1 = f * w1;
    float v2 = f * w2;
    #pragma unroll
    for (int off = 32; off > 0; off >>= 1) {
      v1 += __shfl_down(v1, off, 64);
      v2 += __shfl_down(v2, off, 64);
    }
    if (lane == 0) {
      s1[i] = v1 + b;   // fold bias into s1
      s2[i] = v2;
    }
  }
}

// ---------------- kernel 2: dst histogram ----------------
__global__ __launch_bounds__(256) void hist_dst(
    const int* __restrict__ edst, int* __restrict__ offs, int E) {
  const int e = blockIdx.x * 256 + threadIdx.x;
  if (e < E) atomicAdd(&offs[edst[e]], 1);
}

// ---------------- kernel 3: one-block exclusive scan over N counters --------
__global__ __launch_bounds__(1024) void scan_excl(int* __restrict__ data, int N) {
  __shared__ int tot[1024];
  const int t = threadIdx.x;
  const int items = (N + 1023) >> 10;
  const int b = t * items;
  const int e = min(b + items, N);
  int sum = 0;
  for (int i = b; i < e; ++i) sum += data[i];
  tot[t] = sum;
  __syncthreads();
  // Hillis-Steele inclusive scan over 1024 thread totals
  for (int off = 1; off < 1024; off <<= 1) {
    int u = tot[t] + ((t >= off) ? tot[t - off] : 0);
    __syncthreads();
    tot[t] = u;
    __syncthreads();
  }
  int run = tot[t] - sum;  // exclusive prefix of this thread's chunk
  for (int i = b; i < e; ++i) {
    const int tmp = data[i];
    data[i] = run;
    run += tmp;
  }
}

// ---------------- kernel 4: scatter (src, att) into dst buckets ----------------
// Consumes offs via atomicAdd; afterwards offs[n] == bucket END of node n,
// and bucket BEGIN of node n == offs[n-1] (0 for n==0).
__global__ __launch_bounds__(256) void scatter_att(
    const int* __restrict__ esrc, const int* __restrict__ edst,
    const float* __restrict__ s1, const float* __restrict__ s2,
    int* __restrict__ offs, uint2* __restrict__ ebuf, int E) {
  const int e = blockIdx.x * 256 + threadIdx.x;
  if (e >= E) return;
  const int src = esrc[e];
  const int dst = edst[e];
  const float logit = s1[src] + s2[dst];
  const float a = 1.0f / (1.0f + __expf(-fmaxf(logit, 0.0f)));  // sigmoid(relu)
  const int pos = atomicAdd(&offs[dst], 1);
  ebuf[pos] = make_uint2((unsigned)src, __float_as_uint(a));
}

// ---------------- kernel 5: fused gather-reduce + finalize ----------------
__global__ __launch_bounds__(256) void reduce_finalize(
    const float* __restrict__ feat, const float* __restrict__ norm,
    const int* __restrict__ offs, const uint2* __restrict__ ebuf,
    const float* __restrict__ W_rel, const float* __restrict__ loop_w,
    const float* __restrict__ evolve_w, float* __restrict__ out, int N) {
  __shared__ float sWrel[D * D];   // 16 KB
  __shared__ float sWl[D * D];     // 16 KB
  __shared__ float sWe[D * D];     // 16 KB
  for (int i = threadIdx.x; i < D * D; i += 256) {
    sWrel[i] = W_rel[i];
    sWl[i]   = loop_w[i];
    sWe[i]   = evolve_w[i];
  }
  __syncthreads();

  const int lane = threadIdx.x & 63;
  const int wid  = blockIdx.x * 4 + (threadIdx.x >> 6);
  const int nw   = gridDim.x * 4;
  for (int n = wid; n < N; n += nw) {
    // wave-uniform bucket bounds -> force SGPR so the edge walk uses s_loads
    const int beg = __builtin_amdgcn_readfirstlane(n == 0 ? 0 : offs[n - 1]);
    const int end = __builtin_amdgcn_readfirstlane(offs[n]);
    const float f  = feat[(size_t)n * D + lane];
    const float nr = norm[n];

    float agg = 0.0f;
    int p = beg;
    for (; p + 4 <= end; p += 4) {   // 4 independent gathers in flight
      const uint2 e0 = ebuf[p + 0];
      const uint2 e1 = ebuf[p + 1];
      const uint2 e2 = ebuf[p + 2];
      const uint2 e3 = ebuf[p + 3];
      const float f0 = feat[(size_t)e0.x * D + lane];
      const float f1 = feat[(size_t)e1.x * D + lane];
      const float f2 = feat[(size_t)e2.x * D + lane];
      const float f3 = feat[(size_t)e3.x * D + lane];
      agg += __uint_as_float(e0.y) * f0;
      agg += __uint_as_float(e1.y) * f1;
      agg += __uint_as_float(e2.y) * f2;
      agg += __uint_as_float(e3.y) * f3;
    }
    for (; p < end; ++p) {
      const uint2 en = ebuf[p];
      agg += __uint_as_float(en.y) * feat[(size_t)en.x * D + lane];
    }

    const bool hm = end > beg;   // wave-uniform branch
    float nf, lm = 0.0f;
    if (hm) {
      float a1 = 0.0f;
      #pragma unroll 8
      for (int k = 0; k < D; ++k) {
        const float fb = __shfl(f, k, 64);
        const float pb = __shfl(agg, k, 64);
        a1 += pb * sWrel[k * D + lane];
        lm += fb * sWl[k * D + lane];
      }
      nf = a1 * nr;
    } else {
      #pragma unroll 8
      for (int k = 0; k < D; ++k) {
        const float fb = __shfl(f, k, 64);
        lm += fb * sWe[k * D + lane];
      }
      nf = f * nr;   // zero in-degree keeps old feat
    }
    out[(size_t)n * D + lane] = tanhf(nf + lm);
  }
}

extern "C" void kernel_launch(void* const* d_in, const int* in_sizes, int n_in,
                              void* d_out, int out_size, void* d_ws, size_t ws_size,
                              hipStream_t stream) {
  const float* feat     = (const float*)d_in[0];
  const float* norm     = (const float*)d_in[1];
  const int*   esrc     = (const int*)d_in[2];
  const int*   edst     = (const int*)d_in[3];
  // d_in[4] = etype: no-op permutation per the reference
  const float* W_rel    = (const float*)d_in[5];
  const float* lin_w    = (const float*)d_in[6];
  const float* lin_b    = (const float*)d_in[7];
  const float* loop_w   = (const float*)d_in[8];
  const float* evolve_w = (const float*)d_in[9];
  float* out = (float*)d_out;

  const int N = in_sizes[1];   // norm is [N]
  const int E = in_sizes[2];   // edge_src is [E]

  // workspace: s1[N] f32 | s2[N] f32 | offs[N] i32 | ebuf[E] uint2  (~13.4 MB)
  float* s1   = (float*)d_ws;
  float* s2   = s1 + N;
  int*   offs = (int*)(s2 + N);
  uint2* ebuf = (uint2*)(offs + N);

  hipMemsetAsync(offs, 0, (size_t)N * sizeof(int), stream);
  precompute_att<<<512, 256, 0, stream>>>(feat, lin_w, lin_b, s1, s2, N);
  hist_dst<<<(E + 255) / 256, 256, 0, stream>>>(edst, offs, E);
  scan_excl<<<1, 1024, 0, stream>>>(offs, N);
  scatter_att<<<(E + 255) / 256, 256, 0, stream>>>(esrc, edst, s1, s2, offs, ebuf, E);
  reduce_finalize<<<(N + 1023) / 1024, 256, 0, stream>>>(feat, norm, offs, ebuf,
                                                         W_rel, loop_w, evolve_w,
                                                         out, N);
}

// Round 3
// 413.251 us; speedup vs baseline: 4.1400x; 4.1400x over previous
//
#include <hip/hip_runtime.h>
#include <hip/hip_bf16.h>
#include <math.h>

// LGCN layer, CSR-bucketed (no f32 atomics):
//   agg = segsum(atten*src) @ W_rel          (W_rel commutes out of the sum)
//   att_logit = s1[src] + s2[dst]            (lin_w splits into two per-node dots)
// Pipeline: memset offs -> precompute s1/s2 -> dst histogram -> 2-level scan ->
//           scatter (src,att) into dst buckets -> wave-per-node gather-reduce
//           fused with W_rel/loop matvecs + tanh epilogue.
// R2 fix: reduce_finalize was launched with 49 blocks (Occupancy 2.3%) -> 2048
// blocks + unroll-8 gather; single-block scan -> two-level scan.

#define D 64
#define SCAN_BLOCKS 256
#define SCAN_TPB 256
// items per scan block (ceil(50000 / 256) = 196; keep dynamic via N)

// ---------------- kernel 1: per-node attention scalars ----------------
__global__ __launch_bounds__(256) void precompute_att(
    const float* __restrict__ feat, const float* __restrict__ lin_w,
    const float* __restrict__ lin_b, float* __restrict__ s1,
    float* __restrict__ s2, int N) {
  const int lane = threadIdx.x & 63;
  const int wid  = (blockIdx.x * blockDim.x + threadIdx.x) >> 6;
  const int nw   = (gridDim.x * blockDim.x) >> 6;
  const float w1 = lin_w[lane];
  const float w2 = lin_w[64 + lane];
  const float b  = lin_b[0];
  for (int i = wid; i < N; i += nw) {
    const float f = feat[(size_t)i * D + lane];
    float v1 = f * w1;
    float v2 = f * w2;
    #pragma unroll
    for (int off = 32; off > 0; off >>= 1) {
      v1 += __shfl_down(v1, off, 64);
      v2 += __shfl_down(v2, off, 64);
    }
    if (lane == 0) {
      s1[i] = v1 + b;   // fold bias into s1
      s2[i] = v2;
    }
  }
}

// ---------------- kernel 2: dst histogram ----------------
__global__ __launch_bounds__(256) void hist_dst(
    const int* __restrict__ edst, int* __restrict__ offs, int E) {
  const int e = blockIdx.x * 256 + threadIdx.x;
  if (e < E) atomicAdd(&offs[edst[e]], 1);
}

// ---------------- scan stage A: per-block partial sums ----------------
__global__ __launch_bounds__(SCAN_TPB) void scan_partials(
    const int* __restrict__ data, int* __restrict__ partials, int N, int ipb) {
  __shared__ int red[SCAN_TPB / 64];
  const int b = blockIdx.x * ipb;
  const int e = min(b + ipb, N);
  int sum = 0;
  for (int i = b + threadIdx.x; i < e; i += SCAN_TPB) sum += data[i];
  #pragma unroll
  for (int off = 32; off > 0; off >>= 1) sum += __shfl_down(sum, off, 64);
  if ((threadIdx.x & 63) == 0) red[threadIdx.x >> 6] = sum;
  __syncthreads();
  if (threadIdx.x == 0) {
    int t = 0;
    #pragma unroll
    for (int w = 0; w < SCAN_TPB / 64; ++w) t += red[w];
    partials[blockIdx.x] = t;
  }
}

// ---------------- scan stage B: exclusive-scan the 256 partials ----------------
__global__ __launch_bounds__(SCAN_BLOCKS) void scan_level2(
    int* __restrict__ partials) {
  __shared__ int tot[SCAN_BLOCKS];
  const int t = threadIdx.x;
  int v = partials[t];
  tot[t] = v;
  __syncthreads();
  for (int off = 1; off < SCAN_BLOCKS; off <<= 1) {
    int u = tot[t] + ((t >= off) ? tot[t - off] : 0);
    __syncthreads();
    tot[t] = u;
    __syncthreads();
  }
  partials[t] = tot[t] - v;   // exclusive
}

// ---------------- scan stage C: in-place exclusive scan + add base --------
__global__ __launch_bounds__(1) void scan_addback(
    int* __restrict__ data, const int* __restrict__ partials, int N, int ipb) {
  // one thread per block-chunk would re-serialize; instead: 1 block-chunk per
  // kernel block, one THREAD serial within chunk (ipb ~196) -> use blockIdx
  const int blk = blockIdx.x;
  const int b = blk * ipb;
  const int e = min(b + ipb, N);
  int run = partials[blk];
  for (int i = b; i < e; ++i) {
    const int tmp = data[i];
    data[i] = run;
    run += tmp;
  }
}

// ---------------- kernel 4: scatter (src, att) into dst buckets ----------------
// Consumes offs via atomicAdd; afterwards offs[n] == bucket END of node n,
// and bucket BEGIN of node n == offs[n-1] (0 for n==0).
__global__ __launch_bounds__(256) void scatter_att(
    const int* __restrict__ esrc, const int* __restrict__ edst,
    const float* __restrict__ s1, const float* __restrict__ s2,
    int* __restrict__ offs, uint2* __restrict__ ebuf, int E) {
  const int e = blockIdx.x * 256 + threadIdx.x;
  if (e >= E) return;
  const int src = esrc[e];
  const int dst = edst[e];
  const float logit = s1[src] + s2[dst];
  const float a = 1.0f / (1.0f + __expf(-fmaxf(logit, 0.0f)));  // sigmoid(relu)
  const int pos = atomicAdd(&offs[dst], 1);
  ebuf[pos] = make_uint2((unsigned)src, __float_as_uint(a));
}

// ---------------- kernel 5: fused gather-reduce + finalize ----------------
__global__ __launch_bounds__(256) void reduce_finalize(
    const float* __restrict__ feat, const float* __restrict__ norm,
    const int* __restrict__ offs, const uint2* __restrict__ ebuf,
    const float* __restrict__ W_rel, const float* __restrict__ loop_w,
    const float* __restrict__ evolve_w, float* __restrict__ out, int N) {
  __shared__ float sWrel[D * D];   // 16 KB
  __shared__ float sWl[D * D];     // 16 KB
  __shared__ float sWe[D * D];     // 16 KB
  for (int i = threadIdx.x; i < D * D; i += 256) {
    sWrel[i] = W_rel[i];
    sWl[i]   = loop_w[i];
    sWe[i]   = evolve_w[i];
  }
  __syncthreads();

  const int lane = threadIdx.x & 63;
  const int wid  = blockIdx.x * 4 + (threadIdx.x >> 6);
  const int nw   = gridDim.x * 4;
  for (int n = wid; n < N; n += nw) {
    const int beg = __builtin_amdgcn_readfirstlane(n == 0 ? 0 : offs[n - 1]);
    const int end = __builtin_amdgcn_readfirstlane(offs[n]);
    const float f  = feat[(size_t)n * D + lane];
    const float nr = norm[n];

    float agg = 0.0f;
    int p = beg;
    for (; p + 8 <= end; p += 8) {   // 8 independent 256B gathers in flight
      uint2 ee[8];
      #pragma unroll
      for (int j = 0; j < 8; ++j) ee[j] = ebuf[p + j];
      float ff[8];
      #pragma unroll
      for (int j = 0; j < 8; ++j) ff[j] = feat[(size_t)ee[j].x * D + lane];
      #pragma unroll
      for (int j = 0; j < 8; ++j) agg += __uint_as_float(ee[j].y) * ff[j];
    }
    for (; p < end; ++p) {
      const uint2 en = ebuf[p];
      agg += __uint_as_float(en.y) * feat[(size_t)en.x * D + lane];
    }

    const bool hm = end > beg;   // wave-uniform branch
    float nf, lm = 0.0f;
    if (hm) {
      float a1 = 0.0f;
      #pragma unroll 8
      for (int k = 0; k < D; ++k) {
        const float fb = __shfl(f, k, 64);
        const float pb = __shfl(agg, k, 64);
        a1 += pb * sWrel[k * D + lane];
        lm += fb * sWl[k * D + lane];
      }
      nf = a1 * nr;
    } else {
      #pragma unroll 8
      for (int k = 0; k < D; ++k) {
        const float fb = __shfl(f, k, 64);
        lm += fb * sWe[k * D + lane];
      }
      nf = f * nr;   // zero in-degree keeps old feat
    }
    out[(size_t)n * D + lane] = tanhf(nf + lm);
  }
}

extern "C" void kernel_launch(void* const* d_in, const int* in_sizes, int n_in,
                              void* d_out, int out_size, void* d_ws, size_t ws_size,
                              hipStream_t stream) {
  const float* feat     = (const float*)d_in[0];
  const float* norm     = (const float*)d_in[1];
  const int*   esrc     = (const int*)d_in[2];
  const int*   edst     = (const int*)d_in[3];
  // d_in[4] = etype: no-op permutation per the reference
  const float* W_rel    = (const float*)d_in[5];
  const float* lin_w    = (const float*)d_in[6];
  const float* lin_b    = (const float*)d_in[7];
  const float* loop_w   = (const float*)d_in[8];
  const float* evolve_w = (const float*)d_in[9];
  float* out = (float*)d_out;

  const int N = in_sizes[1];   // norm is [N]
  const int E = in_sizes[2];   // edge_src is [E]

  // workspace: s1[N] | s2[N] | offs[N] | partials[256] | ebuf[E] uint2
  float* s1       = (float*)d_ws;
  float* s2       = s1 + N;
  int*   offs     = (int*)(s2 + N);
  int*   partials = offs + N;
  uint2* ebuf     = (uint2*)(partials + SCAN_BLOCKS);

  const int ipb = (N + SCAN_BLOCKS - 1) / SCAN_BLOCKS;  // items per scan chunk

  hipMemsetAsync(offs, 0, (size_t)N * sizeof(int), stream);
  precompute_att<<<512, 256, 0, stream>>>(feat, lin_w, lin_b, s1, s2, N);
  hist_dst<<<(E + 255) / 256, 256, 0, stream>>>(edst, offs, E);
  scan_partials<<<SCAN_BLOCKS, SCAN_TPB, 0, stream>>>(offs, partials, N, ipb);
  scan_level2<<<1, SCAN_BLOCKS, 0, stream>>>(partials);
  scan_addback<<<SCAN_BLOCKS, 1, 0, stream>>>(offs, partials, N, ipb);
  scatter_att<<<(E + 255) / 256, 256, 0, stream>>>(esrc, edst, s1, s2, offs, ebuf, E);
  reduce_finalize<<<2048, 256, 0, stream>>>(feat, norm, offs, ebuf,
                                            W_rel, loop_w, evolve_w, out, N);
}

// Round 4
// 358.405 us; speedup vs baseline: 4.7736x; 1.1530x over previous
//
#include <hip/hip_runtime.h>
#include <hip/hip_bf16.h>
#include <math.h>

// LGCN layer, CSR-bucketed (no f32 atomics):
//   agg = segsum(atten*src) @ W_rel          (W_rel commutes out of the sum)
//   att_logit = s1[src] + s2[dst]            (lin_w splits into two per-node dots)
// Pipeline: precompute s1/s2 (+zero offs) -> dst histogram -> 3-stage scan ->
//           scatter (src,att) into dst buckets -> wave-per-node gather-reduce
//           fused with W_rel/loop matvecs + tanh epilogue.
// R3: reduce_finalize occupancy was LDS-capped at 26% (3 blk/CU @ 48KB) ->
//     weights now read straight from global (L1-resident, wave-uniform-k
//     coalesced); scan stage C was 1 thread/chunk serial (~40us) -> 256-thread
//     block scan; offs-zeroing fused into precompute_att.

#define D 64
#define SCAN_BLOCKS 256
#define SCAN_TPB 256

// ---------------- kernel 1: per-node attention scalars + zero offs ----------
__global__ __launch_bounds__(256) void precompute_att(
    const float* __restrict__ feat, const float* __restrict__ lin_w,
    const float* __restrict__ lin_b, float* __restrict__ s1,
    float* __restrict__ s2, int* __restrict__ offs, int N) {
  // zero the histogram counters (ws is poisoned 0xAA before every launch)
  const int gt = blockIdx.x * 256 + threadIdx.x;
  for (int i = gt; i < N; i += gridDim.x * 256) offs[i] = 0;

  const int lane = threadIdx.x & 63;
  const int wid  = (blockIdx.x * blockDim.x + threadIdx.x) >> 6;
  const int nw   = (gridDim.x * blockDim.x) >> 6;
  const float w1 = lin_w[lane];
  const float w2 = lin_w[64 + lane];
  const float b  = lin_b[0];
  for (int i = wid; i < N; i += nw) {
    const float f = feat[(size_t)i * D + lane];
    float v1 = f * w1;
    float v2 = f * w2;
    #pragma unroll
    for (int off = 32; off > 0; off >>= 1) {
      v1 += __shfl_down(v1, off, 64);
      v2 += __shfl_down(v2, off, 64);
    }
    if (lane == 0) {
      s1[i] = v1 + b;   // fold bias into s1
      s2[i] = v2;
    }
  }
}

// ---------------- kernel 2: dst histogram ----------------
__global__ __launch_bounds__(256) void hist_dst(
    const int* __restrict__ edst, int* __restrict__ offs, int E) {
  const int e = blockIdx.x * 256 + threadIdx.x;
  if (e < E) atomicAdd(&offs[edst[e]], 1);
}

// ---------------- scan stage A: per-chunk partial sums ----------------
__global__ __launch_bounds__(SCAN_TPB) void scan_partials(
    const int* __restrict__ data, int* __restrict__ partials, int N, int ipb) {
  __shared__ int red[SCAN_TPB / 64];
  const int b = blockIdx.x * ipb;
  const int e = min(b + ipb, N);
  int sum = 0;
  for (int i = b + threadIdx.x; i < e; i += SCAN_TPB) sum += data[i];
  #pragma unroll
  for (int off = 32; off > 0; off >>= 1) sum += __shfl_down(sum, off, 64);
  if ((threadIdx.x & 63) == 0) red[threadIdx.x >> 6] = sum;
  __syncthreads();
  if (threadIdx.x == 0) {
    int t = 0;
    #pragma unroll
    for (int w = 0; w < SCAN_TPB / 64; ++w) t += red[w];
    partials[blockIdx.x] = t;
  }
}

// ---------------- scan stage B: exclusive-scan the 256 partials ----------------
__global__ __launch_bounds__(SCAN_BLOCKS) void scan_level2(
    int* __restrict__ partials) {
  __shared__ int tot[SCAN_BLOCKS];
  const int t = threadIdx.x;
  int v = partials[t];
  tot[t] = v;
  __syncthreads();
  for (int off = 1; off < SCAN_BLOCKS; off <<= 1) {
    int u = tot[t] + ((t >= off) ? tot[t - off] : 0);
    __syncthreads();
    tot[t] = u;
    __syncthreads();
  }
  partials[t] = tot[t] - v;   // exclusive
}

// ---------------- scan stage C: parallel in-chunk exclusive scan + base ------
// requires ipb <= SCAN_TPB (N=50000 -> ipb=196)
__global__ __launch_bounds__(SCAN_TPB) void scan_chunks(
    int* __restrict__ data, const int* __restrict__ partials, int N, int ipb) {
  __shared__ int tot[SCAN_TPB];
  const int t = threadIdx.x;
  const int b = blockIdx.x * ipb;
  const int i = b + t;
  const int v = (t < ipb && i < N) ? data[i] : 0;
  tot[t] = v;
  __syncthreads();
  for (int off = 1; off < SCAN_TPB; off <<= 1) {
    int u = tot[t] + ((t >= off) ? tot[t - off] : 0);
    __syncthreads();
    tot[t] = u;
    __syncthreads();
  }
  if (t < ipb && i < N) data[i] = tot[t] - v + partials[blockIdx.x];
}

// ---------------- kernel 4: scatter (src, att) into dst buckets ----------------
// Consumes offs via atomicAdd; afterwards offs[n] == bucket END of node n,
// and bucket BEGIN of node n == offs[n-1] (0 for n==0).
__global__ __launch_bounds__(256) void scatter_att(
    const int* __restrict__ esrc, const int* __restrict__ edst,
    const float* __restrict__ s1, const float* __restrict__ s2,
    int* __restrict__ offs, uint2* __restrict__ ebuf, int E) {
  const int e = blockIdx.x * 256 + threadIdx.x;
  if (e >= E) return;
  const int src = esrc[e];
  const int dst = edst[e];
  const float logit = s1[src] + s2[dst];
  const float a = 1.0f / (1.0f + __expf(-fmaxf(logit, 0.0f)));  // sigmoid(relu)
  const int pos = atomicAdd(&offs[dst], 1);
  ebuf[pos] = make_uint2((unsigned)src, __float_as_uint(a));
}

// ---------------- kernel 5: fused gather-reduce + finalize ----------------
// No LDS: weight reads are wave-uniform-k coalesced 256B loads -> L1-resident.
__global__ __launch_bounds__(256) void reduce_finalize(
    const float* __restrict__ feat, const float* __restrict__ norm,
    const int* __restrict__ offs, const uint2* __restrict__ ebuf,
    const float* __restrict__ W_rel, const float* __restrict__ loop_w,
    const float* __restrict__ evolve_w, float* __restrict__ out, int N) {
  const int lane = threadIdx.x & 63;
  const int wid  = blockIdx.x * 4 + (threadIdx.x >> 6);
  const int nw   = gridDim.x * 4;
  for (int n = wid; n < N; n += nw) {
    const int beg = __builtin_amdgcn_readfirstlane(n == 0 ? 0 : offs[n - 1]);
    const int end = __builtin_amdgcn_readfirstlane(offs[n]);
    const float f  = feat[(size_t)n * D + lane];
    const float nr = norm[n];

    float agg = 0.0f;
    int p = beg;
    for (; p + 8 <= end; p += 8) {   // 8 independent 256B gathers in flight
      uint2 ee[8];
      #pragma unroll
      for (int j = 0; j < 8; ++j) ee[j] = ebuf[p + j];
      float ff[8];
      #pragma unroll
      for (int j = 0; j < 8; ++j) ff[j] = feat[(size_t)ee[j].x * D + lane];
      #pragma unroll
      for (int j = 0; j < 8; ++j) agg += __uint_as_float(ee[j].y) * ff[j];
    }
    for (; p < end; ++p) {
      const uint2 en = ebuf[p];
      agg += __uint_as_float(en.y) * feat[(size_t)en.x * D + lane];
    }

    const bool hm = end > beg;   // wave-uniform branch
    float nf, lm = 0.0f;
    if (hm) {
      float a1 = 0.0f;
      #pragma unroll 8
      for (int k = 0; k < D; ++k) {
        const float fb = __shfl(f, k, 64);
        const float pb = __shfl(agg, k, 64);
        a1 += pb * W_rel[k * D + lane];
        lm += fb * loop_w[k * D + lane];
      }
      nf = a1 * nr;
    } else {
      #pragma unroll 8
      for (int k = 0; k < D; ++k) {
        const float fb = __shfl(f, k, 64);
        lm += fb * evolve_w[k * D + lane];
      }
      nf = f * nr;   // zero in-degree keeps old feat
    }
    out[(size_t)n * D + lane] = tanhf(nf + lm);
  }
}

extern "C" void kernel_launch(void* const* d_in, const int* in_sizes, int n_in,
                              void* d_out, int out_size, void* d_ws, size_t ws_size,
                              hipStream_t stream) {
  const float* feat     = (const float*)d_in[0];
  const float* norm     = (const float*)d_in[1];
  const int*   esrc     = (const int*)d_in[2];
  const int*   edst     = (const int*)d_in[3];
  // d_in[4] = etype: no-op permutation per the reference
  const float* W_rel    = (const float*)d_in[5];
  const float* lin_w    = (const float*)d_in[6];
  const float* lin_b    = (const float*)d_in[7];
  const float* loop_w   = (const float*)d_in[8];
  const float* evolve_w = (const float*)d_in[9];
  float* out = (float*)d_out;

  const int N = in_sizes[1];   // norm is [N]
  const int E = in_sizes[2];   // edge_src is [E]

  // workspace: s1[N] | s2[N] | offs[N] | partials[256] | ebuf[E] uint2
  float* s1       = (float*)d_ws;
  float* s2       = s1 + N;
  int*   offs     = (int*)(s2 + N);
  int*   partials = offs + N;
  uint2* ebuf     = (uint2*)(partials + SCAN_BLOCKS);

  const int ipb = (N + SCAN_BLOCKS - 1) / SCAN_BLOCKS;  // 196 for N=50000

  precompute_att<<<512, 256, 0, stream>>>(feat, lin_w, lin_b, s1, s2, offs, N);
  hist_dst<<<(E + 255) / 256, 256, 0, stream>>>(edst, offs, E);
  scan_partials<<<SCAN_BLOCKS, SCAN_TPB, 0, stream>>>(offs, partials, N, ipb);
  scan_level2<<<1, SCAN_BLOCKS, 0, stream>>>(partials);
  scan_chunks<<<SCAN_BLOCKS, SCAN_TPB, 0, stream>>>(offs, partials, N, ipb);
  scatter_att<<<(E + 255) / 256, 256, 0, stream>>>(esrc, edst, s1, s2, offs, ebuf, E);
  reduce_finalize<<<2048, 256, 0, stream>>>(feat, norm, offs, ebuf,
                                            W_rel, loop_w, evolve_w, out, N);
}